// Round 11
// baseline (12058.619 us; speedup 1.0000x reference)
//
#include <hip/hip_runtime.h>
#include <hip/hip_fp16.h>

#define S_LEN 2048
#define BATCH 64
#define VOC   32000
#define HID   1024

typedef __attribute__((ext_vector_type(4))) float          f32x4;
typedef __attribute__((ext_vector_type(8))) _Float16       half8;
typedef __attribute__((ext_vector_type(2))) int            int2v;

union PunH { uint4 u; half8 h; };

// ---------------------------------------------------------------------------
// prep: emb->fp16, W_ih->fp16, W_hh->fp16 hi/lo; zero h slot 0, per-wave
// flags (1024 ints), zbuf. Runs every launch (replay-safe).
// ---------------------------------------------------------------------------
__global__ void prep_kernel(const float* __restrict__ emb,
                            const float* __restrict__ wih,
                            const float* __restrict__ whh,
                            __half* __restrict__ embh,
                            __half* __restrict__ wihh,
                            unsigned short* __restrict__ whh_hi,
                            unsigned short* __restrict__ whh_lo,
                            unsigned short* __restrict__ hbuf,
                            unsigned int* __restrict__ zbuf,
                            int* __restrict__ flags)
{
    long i = (long)blockIdx.x * blockDim.x + threadIdx.x;
    if (i < (long)VOC * HID) embh[i] = __float2half(emb[i]);
    if (i < (long)HID * HID) {
        wihh[i] = __float2half(wih[i]);
        float wv = whh[i];
        __half hi = __float2half(wv);
        __half lo = __float2half(wv - __half2float(hi));
        whh_hi[i] = __half_as_ushort(hi);
        whh_lo[i] = __half_as_ushort(lo);
    }
    if (i < BATCH * HID) hbuf[i] = 0;   // h_0 = 0 (fp16), ring slot 0
    if (i < 1024) flags[i] = 0;         // [ (g*32+w)*4 + wave ] per-wave flags
    if (i < 256) zbuf[i] = 0u;          // zero pad for inactive-lane loads
}

// ---------------------------------------------------------------------------
// xp GEMM (unchanged, proven): fp16 MFMA 16x16x32, 128x128 tile.
// Output in phase-2-blocked layout: [s][g][w][r][kk].
// ---------------------------------------------------------------------------
__global__ void __launch_bounds__(256)
xp_gemm(const int* __restrict__ tok,
        const __half* __restrict__ embh,
        const __half* __restrict__ wihh,
        const float* __restrict__ b_ih,
        __half* __restrict__ xp)
{
    __shared__ __half Asm[128][72];
    __shared__ __half Bsm[128][72];
    __shared__ int toks[128];

    const int tid   = threadIdx.x;
    const int ntile = blockIdx.x;   // 0..7
    const int mtile = blockIdx.y;   // 0..1023

    if (tid < 128) {
        int t = tok[mtile * 128 + tid];
        toks[tid] = (t < 0) ? 0 : (t >= VOC ? VOC - 1 : t);
    }
    __syncthreads();

    const int lane = tid & 63, wv = tid >> 6;
    const int mv = (wv & 1) * 64, nv = (wv >> 1) * 64;

    f32x4 acc[4][4];
    #pragma unroll
    for (int a = 0; a < 4; a++)
        #pragma unroll
        for (int b = 0; b < 4; b++) acc[a][b] = (f32x4)0.0f;

    const int srow = tid & 127;
    const int shalf = (tid >> 7) * 32;
    const __half* gA = embh + (size_t)toks[srow] * HID + shalf;
    const __half* gB = wihh + (size_t)(ntile * 128 + srow) * HID + shalf;

    for (int kb = 0; kb < 16; kb++) {
        const uint4* pa = (const uint4*)(gA + kb * 64);
        const uint4* pb = (const uint4*)(gB + kb * 64);
        uint4 va0 = pa[0], va1 = pa[1], va2 = pa[2], va3 = pa[3];
        uint4 vb0 = pb[0], vb1 = pb[1], vb2 = pb[2], vb3 = pb[3];
        uint4* la = (uint4*)&Asm[srow][shalf];
        uint4* lb = (uint4*)&Bsm[srow][shalf];
        la[0] = va0; la[1] = va1; la[2] = va2; la[3] = va3;
        lb[0] = vb0; lb[1] = vb1; lb[2] = vb2; lb[3] = vb3;
        __syncthreads();

        #pragma unroll
        for (int ks = 0; ks < 2; ks++) {
            half8 af[4], bf[4];
            const int kc = ks * 32 + (lane >> 4) * 8;
            #pragma unroll
            for (int m = 0; m < 4; m++)
                af[m] = *(const half8*)&Asm[mv + m * 16 + (lane & 15)][kc];
            #pragma unroll
            for (int n = 0; n < 4; n++)
                bf[n] = *(const half8*)&Bsm[nv + n * 16 + (lane & 15)][kc];
            #pragma unroll
            for (int m = 0; m < 4; m++)
                #pragma unroll
                for (int n = 0; n < 4; n++)
                    acc[m][n] = __builtin_amdgcn_mfma_f32_16x16x32_f16(
                        af[m], bf[n], acc[m][n], 0, 0, 0);
        }
        __syncthreads();
    }

    #pragma unroll
    for (int n = 0; n < 4; n++) {
        const int ng = ntile * 128 + nv + n * 16 + (lane & 15);
        const float bi = b_ih[ng];
        const int wg = ng >> 5, kk = ng & 31;
        #pragma unroll
        for (int m = 0; m < 4; m++) {
            #pragma unroll
            for (int i = 0; i < 4; i++) {
                const int mg = mtile * 128 + mv + m * 16 + (lane >> 4) * 4 + i;
                const int s = mg >> 6, b = mg & 63;
                const size_t off = ((size_t)(s * 8 + (b >> 3)) * 32 + wg) * 256
                                 + (b & 7) * 32 + kk;
                xp[off] = __float2half(acc[m][n][i] + bi);
            }
        }
    }
}

// ---------------------------------------------------------------------------
// recurrence: r7's proven protocol with PER-WAVE FLAGS (no barrier B).
// Each wave drains its own h stores (in-asm vmcnt(0)) then stores its own
// flag — the invariant "flag => rows committed" holds per-wave without a
// WG barrier. Consumers poll all 128 wave-flags (32 WGs x 4 waves, two per
// lane via dwordx2). The poll also protects the red/LDS reuse that barrier
// B used to cover: a wave reaches iter t+1's red-write only after every
// wave's t+1 flag is up, i.e. after they finished reading red for t.
// Poll-then-load ordering, sc0 sc1 scope, math: r7-verbatim.
// ---------------------------------------------------------------------------
__global__ void __launch_bounds__(256, 1)
recur_kernel(const __half* __restrict__ xp,
             const unsigned short* __restrict__ whh_hi,
             const unsigned short* __restrict__ whh_lo,
             const float* __restrict__ b_hh,
             unsigned short* hbuf,
             const unsigned int* zbuf, int* flags)
{
    extern __shared__ char smem[];                 // 136192 bytes
    float*  red  = (float*)(smem + 131072);        // [4][8][32]
    __half* ring = (__half*)(smem + 135168);       // [2][256]

    const int tid  = threadIdx.x;
    const int lane = tid & 63;
    const int wv   = tid >> 6;
    const int g    = blockIdx.x >> 5;
    const int w    = blockIdx.x & 31;

    { // load W_hh fp16 hi/lo slice into LDS, swizzled: byte ^= (row&7)<<4
        const int r  = tid >> 3;
        const int c0 = (tid & 7) * 128;
        const unsigned short* ghi = whh_hi + (size_t)(w * 32 + r) * HID + c0;
        const unsigned short* glo = whh_lo + (size_t)(w * 32 + r) * HID + c0;
        #pragma unroll
        for (int j = 0; j < 16; j++) {
            uint4 vhi = ((const uint4*)ghi)[j];
            uint4 vlo = ((const uint4*)glo)[j];
            int byte = r * 2048 + c0 * 2 + j * 16;
            byte ^= (r & 7) << 4;
            *(uint4*)(smem + byte)         = vhi;
            *(uint4*)(smem + 65536 + byte) = vlo;
        }
    }
    // xp prologue: ring slot 0 = xp[t=0]; issue prefetch of xp[t=1]
    uint4 xn_next;
    if (wv == 0 && tid < 32) {
        const size_t b0 = ((size_t)g * 32 + w) * 256;
        uint4 v0 = ((const uint4*)(xp + b0))[tid];
        *(uint4*)&ring[tid * 8] = v0;
        xn_next = ((const uint4*)(xp + ((size_t)(8 + g) * 32 + (size_t)w) * 256))[tid];
    }
    __syncthreads();

    const bool act = (lane & 15) < 8;
    const int  ar  = lane & 15;
    const int  ak  = (lane >> 4) * 8;
    const float bhh = b_hh[w * 32 + (tid & 31)];
    // poll targets: lane L covers WG (L&31), wave pair (L>>5)*2 .. +1
    const int* const pollp = flags + g * 128 + (lane & 31) * 4 + (lane >> 5) * 2;
    int* const myflag = flags + g * 128 + w * 4 + wv;

    for (int t = 0; t < S_LEN; t++) {
        // 1) ring write for t+1 + xp prefetch for t+2 (independent work,
        //    moved OFF the post-poll critical path)
        if (wv == 0 && tid < 32) {
            if (t + 1 < S_LEN)
                *(uint4*)&ring[((t + 1) & 1) * 256 + tid * 8] = xn_next;
            if (t + 2 < S_LEN)
                xn_next = ((const uint4*)(xp
                    + ((size_t)((t + 2) * 8 + g) * 32 + (size_t)w) * 256))[tid];
        }

        // 2) poll all 128 per-wave flags (2 per lane, dwordx2). Bound 4096:
        //    sync failure -> fast wrong answer, never a timeout.
        {
            int2v fv; int spin = 0;
            do {
                asm volatile("global_load_dwordx2 %0, %1, off sc0 sc1\n\t"
                             "s_waitcnt vmcnt(0)"
                             : "=v"(fv) : "v"(pollp) : "memory");
            } while (__any(fv.x < t || fv.y < t) && ++spin < 4096);
        }

        // 3) load h_t fragments: single fp16 stream from IC (sc0 sc1), zero
        //    pad for inactive rows. 8x dwordx4 batched, one vmcnt(0).
        const size_t hoff = (size_t)(t & 3) * (BATCH * HID)
                          + (size_t)(g * 8 + (act ? ar : 0)) * HID + wv * 256 + ak;
        const unsigned short* ph = act ? (hbuf + hoff) : (const unsigned short*)zbuf;
        uint4 c[8];
        asm volatile(
            "global_load_dwordx4 %0, %8, off sc0 sc1\n\t"
            "global_load_dwordx4 %1, %8, off offset:64 sc0 sc1\n\t"
            "global_load_dwordx4 %2, %8, off offset:128 sc0 sc1\n\t"
            "global_load_dwordx4 %3, %8, off offset:192 sc0 sc1\n\t"
            "global_load_dwordx4 %4, %8, off offset:256 sc0 sc1\n\t"
            "global_load_dwordx4 %5, %8, off offset:320 sc0 sc1\n\t"
            "global_load_dwordx4 %6, %8, off offset:384 sc0 sc1\n\t"
            "global_load_dwordx4 %7, %8, off offset:448 sc0 sc1\n\t"
            "s_waitcnt vmcnt(0)"
            : "=&v"(c[0]), "=&v"(c[1]), "=&v"(c[2]), "=&v"(c[3]),
              "=&v"(c[4]), "=&v"(c[5]), "=&v"(c[6]), "=&v"(c[7])
            : "v"(ph)
            : "memory");

        // 4) fp16 MFMA: h * (W_hi + W_lo), 2 MFMAs per (kk,j)
        f32x4 acc_h[2], acc_l[2];
        #pragma unroll
        for (int j = 0; j < 2; j++) {
            acc_h[j] = (f32x4)0.0f; acc_l[j] = (f32x4)0.0f;
        }
        const int kbyte0 = (wv * 256 + ak) * 2;
        #pragma unroll
        for (int kk = 0; kk < 8; kk++) {
            PunH pa; pa.u = c[kk];
            const half8 af = pa.h;
            #pragma unroll
            for (int j = 0; j < 2; j++) {
                const int rloc = j * 16 + (lane & 15);
                int bb = rloc * 2048 + kbyte0 + kk * 64;
                bb ^= (rloc & 7) << 4;
                PunH pbh; pbh.u = *(const uint4*)(smem + bb);
                PunH pbl; pbl.u = *(const uint4*)(smem + 65536 + bb);
                acc_h[j] = __builtin_amdgcn_mfma_f32_16x16x32_f16(af, pbh.h, acc_h[j], 0, 0, 0);
                acc_l[j] = __builtin_amdgcn_mfma_f32_16x16x32_f16(af, pbl.h, acc_l[j], 0, 0, 0);
            }
        }

        // 5) cross-wave K reduction into LDS
        if (lane < 32) {
            #pragma unroll
            for (int j = 0; j < 2; j++) {
                const f32x4 d = acc_h[j] + acc_l[j];
                const int col = j * 16 + (lane & 15);
                #pragma unroll
                for (int i = 0; i < 4; i++) {
                    const int r = (lane >> 4) * 4 + i;
                    red[(wv * 8 + r) * 32 + col] = d[i];
                }
            }
        }
        __syncthreads();   // barrier A (the only barrier per step)

        // 6) finish: z -> tanh -> fp16 publish + in-asm per-wave drain, then
        //    this wave's flag (no barrier B — invariant is wave-local).
        {
            const int r = tid >> 5, n = tid & 31;
            float z = red[r * 32 + n] + red[(8 + r) * 32 + n]
                    + red[(16 + r) * 32 + n] + red[(24 + r) * 32 + n];
            z += __half2float(ring[(t & 1) * 256 + tid]) + bhh;
            const float h = tanhf(z);
            const unsigned int hv = __half_as_ushort(__float2half(h));
            const size_t off = (size_t)((t + 1) & 3) * (BATCH * HID)
                             + (size_t)(g * 8 + r) * HID + w * 32 + n;
            asm volatile("global_store_short %0, %1, off sc0 sc1\n\t"
                         "s_waitcnt vmcnt(0)"
                         :: "v"(hbuf + off), "v"(hv) : "memory");
        }
        if (lane == 0) {
            const int fv2 = t + 1;
            asm volatile("global_store_dword %0, %1, off sc0 sc1"
                         :: "v"(myflag), "v"(fv2) : "memory");
        }
    }
}

// ---------------------------------------------------------------------------
// classifier on h_final (slot (2048&3)=0), fp16 h
// ---------------------------------------------------------------------------
__global__ void cls_kernel(const unsigned short* __restrict__ hbuf,
                           const float* __restrict__ wfc,
                           const float* __restrict__ bfc,
                           float* __restrict__ out)
{
    const int b = blockIdx.x, lane = threadIdx.x;
    const unsigned short* hp = hbuf + (size_t)b * HID;  // slot 0
    float p0 = 0.f, p1 = 0.f;
    for (int k = lane; k < HID; k += 64) {
        const float h = __half2float(__ushort_as_half(hp[k]));
        p0 += h * wfc[k];
        p1 += h * wfc[HID + k];
    }
    #pragma unroll
    for (int s = 32; s; s >>= 1) {
        p0 += __shfl_down(p0, s);
        p1 += __shfl_down(p1, s);
    }
    if (lane == 0) {
        out[b * 2 + 0] = p0 + bfc[0];
        out[b * 2 + 1] = p1 + bfc[1];
    }
}

// ---------------------------------------------------------------------------
extern "C" void kernel_launch(void* const* d_in, const int* in_sizes, int n_in,
                              void* d_out, int out_size, void* d_ws, size_t ws_size,
                              hipStream_t stream)
{
    const int*   tok = (const int*)d_in[0];
    const float* emb = (const float*)d_in[1];
    const float* wih = (const float*)d_in[2];
    const float* whh = (const float*)d_in[3];
    const float* bih = (const float*)d_in[4];
    const float* bhh = (const float*)d_in[5];
    const float* wfc = (const float*)d_in[6];
    const float* bfc = (const float*)d_in[7];
    float* out = (float*)d_out;

    char* ws = (char*)d_ws;
    size_t off = 0;
    auto alloc = [&](size_t bytes) {
        char* p = ws + off;
        off += (bytes + 255) & ~(size_t)255;
        return p;
    };
    __half*         xp      = (__half*)alloc((size_t)S_LEN * BATCH * HID * 2);
    __half*         embh    = (__half*)alloc((size_t)VOC * HID * 2);
    __half*         wihh    = (__half*)alloc((size_t)HID * HID * 2);
    unsigned short* whh_hi  = (unsigned short*)alloc((size_t)HID * HID * 2);
    unsigned short* whh_lo  = (unsigned short*)alloc((size_t)HID * HID * 2);
    unsigned short* hbuf    = (unsigned short*)alloc((size_t)4 * BATCH * HID * 2);
    unsigned int*   zbuf    = (unsigned int*)alloc(1024);
    int*            flags   = (int*)alloc(4096);

    if (off > ws_size) {
        hipMemsetAsync(d_out, 0, (size_t)out_size * sizeof(float), stream);
        return;
    }

    prep_kernel<<<dim3((VOC * HID) / 256), 256, 0, stream>>>(
        emb, wih, whh, embh, wihh, whh_hi, whh_lo, hbuf, zbuf, flags);

    xp_gemm<<<dim3(8, 1024), 256, 0, stream>>>(tok, embh, wihh, bih, xp);

    const unsigned int shmem = 136192;
    hipFuncSetAttribute(reinterpret_cast<const void*>(recur_kernel),
                        hipFuncAttributeMaxDynamicSharedMemorySize, (int)shmem);
    void* args[] = { (void*)&xp, (void*)&whh_hi, (void*)&whh_lo, (void*)&bhh,
                     (void*)&hbuf, (void*)&zbuf, (void*)&flags };
    hipLaunchCooperativeKernel(reinterpret_cast<const void*>(recur_kernel),
                               dim3(256), dim3(256), args, shmem, stream);

    cls_kernel<<<dim3(64), 64, 0, stream>>>(hbuf, wfc, bfc, out);
}

// Round 12
// 7385.278 us; speedup vs baseline: 1.6328x; 1.6328x over previous
//
#include <hip/hip_runtime.h>
#include <hip/hip_fp16.h>

#define S_LEN 2048
#define BATCH 64
#define VOC   32000
#define HID   1024

typedef __attribute__((ext_vector_type(4))) float          f32x4;
typedef __attribute__((ext_vector_type(8))) _Float16       half8;

union PunH { uint4 u; half8 h; };

// ---------------------------------------------------------------------------
// prep: emb->fp16, W_ih->fp16, W_hh->fp16 hi/lo; zero h slot 0, flags, zbuf.
// Runs every launch (replay-safe).
// ---------------------------------------------------------------------------
__global__ void prep_kernel(const float* __restrict__ emb,
                            const float* __restrict__ wih,
                            const float* __restrict__ whh,
                            __half* __restrict__ embh,
                            __half* __restrict__ wihh,
                            unsigned short* __restrict__ whh_hi,
                            unsigned short* __restrict__ whh_lo,
                            unsigned short* __restrict__ hbuf,
                            unsigned int* __restrict__ zbuf,
                            int* __restrict__ flags)
{
    long i = (long)blockIdx.x * blockDim.x + threadIdx.x;
    if (i < (long)VOC * HID) embh[i] = __float2half(emb[i]);
    if (i < (long)HID * HID) {
        wihh[i] = __float2half(wih[i]);
        float wv = whh[i];
        __half hi = __float2half(wv);
        __half lo = __float2half(wv - __half2float(hi));
        whh_hi[i] = __half_as_ushort(hi);
        whh_lo[i] = __half_as_ushort(lo);
    }
    if (i < BATCH * HID) hbuf[i] = 0;   // h_0 = 0 (fp16), ring slot 0
    if (i < 512) flags[i] = 0;
    if (i < 256) zbuf[i] = 0u;          // zero pad for inactive-lane loads
}

// ---------------------------------------------------------------------------
// xp GEMM (unchanged, proven): fp16 MFMA 16x16x32, 128x128 tile.
// Output in phase-2-blocked layout: [s][g][w][r][kk].
// ---------------------------------------------------------------------------
__global__ void __launch_bounds__(256)
xp_gemm(const int* __restrict__ tok,
        const __half* __restrict__ embh,
        const __half* __restrict__ wihh,
        const float* __restrict__ b_ih,
        __half* __restrict__ xp)
{
    __shared__ __half Asm[128][72];
    __shared__ __half Bsm[128][72];
    __shared__ int toks[128];

    const int tid   = threadIdx.x;
    const int ntile = blockIdx.x;   // 0..7
    const int mtile = blockIdx.y;   // 0..1023

    if (tid < 128) {
        int t = tok[mtile * 128 + tid];
        toks[tid] = (t < 0) ? 0 : (t >= VOC ? VOC - 1 : t);
    }
    __syncthreads();

    const int lane = tid & 63, wv = tid >> 6;
    const int mv = (wv & 1) * 64, nv = (wv >> 1) * 64;

    f32x4 acc[4][4];
    #pragma unroll
    for (int a = 0; a < 4; a++)
        #pragma unroll
        for (int b = 0; b < 4; b++) acc[a][b] = (f32x4)0.0f;

    const int srow = tid & 127;
    const int shalf = (tid >> 7) * 32;
    const __half* gA = embh + (size_t)toks[srow] * HID + shalf;
    const __half* gB = wihh + (size_t)(ntile * 128 + srow) * HID + shalf;

    for (int kb = 0; kb < 16; kb++) {
        const uint4* pa = (const uint4*)(gA + kb * 64);
        const uint4* pb = (const uint4*)(gB + kb * 64);
        uint4 va0 = pa[0], va1 = pa[1], va2 = pa[2], va3 = pa[3];
        uint4 vb0 = pb[0], vb1 = pb[1], vb2 = pb[2], vb3 = pb[3];
        uint4* la = (uint4*)&Asm[srow][shalf];
        uint4* lb = (uint4*)&Bsm[srow][shalf];
        la[0] = va0; la[1] = va1; la[2] = va2; la[3] = va3;
        lb[0] = vb0; lb[1] = vb1; lb[2] = vb2; lb[3] = vb3;
        __syncthreads();

        #pragma unroll
        for (int ks = 0; ks < 2; ks++) {
            half8 af[4], bf[4];
            const int kc = ks * 32 + (lane >> 4) * 8;
            #pragma unroll
            for (int m = 0; m < 4; m++)
                af[m] = *(const half8*)&Asm[mv + m * 16 + (lane & 15)][kc];
            #pragma unroll
            for (int n = 0; n < 4; n++)
                bf[n] = *(const half8*)&Bsm[nv + n * 16 + (lane & 15)][kc];
            #pragma unroll
            for (int m = 0; m < 4; m++)
                #pragma unroll
                for (int n = 0; n < 4; n++)
                    acc[m][n] = __builtin_amdgcn_mfma_f32_16x16x32_f16(
                        af[m], bf[n], acc[m][n], 0, 0, 0);
        }
        __syncthreads();
    }

    #pragma unroll
    for (int n = 0; n < 4; n++) {
        const int ng = ntile * 128 + nv + n * 16 + (lane & 15);
        const float bi = b_ih[ng];
        const int wg = ng >> 5, kk = ng & 31;
        #pragma unroll
        for (int m = 0; m < 4; m++) {
            #pragma unroll
            for (int i = 0; i < 4; i++) {
                const int mg = mtile * 128 + mv + m * 16 + (lane >> 4) * 4 + i;
                const int s = mg >> 6, b = mg & 63;
                const size_t off = ((size_t)(s * 8 + (b >> 3)) * 32 + wg) * 256
                                 + (b & 7) * 32 + kk;
                xp[off] = __float2half(acc[m][n][i] + bi);
            }
        }
    }
}

// ---------------------------------------------------------------------------
// recurrence: r7's PROVEN protocol verbatim (static roles; h/flags at IC
// scope sc0 sc1; store -> in-asm drain -> barrier -> flag; poll-then-load),
// with ONE protocol-preserving micro-opt: the first poll sample is issued
// before the ring LDS write, which executes in its shadow (rule #18:
// sched_barrier(0) after the waitcnt before using the sampled value).
// ---------------------------------------------------------------------------
__global__ void __launch_bounds__(256, 1)
recur_kernel(const __half* __restrict__ xp,
             const unsigned short* __restrict__ whh_hi,
             const unsigned short* __restrict__ whh_lo,
             const float* __restrict__ b_hh,
             unsigned short* hbuf,
             const unsigned int* zbuf, int* flags)
{
    extern __shared__ char smem[];                 // 136192 bytes
    float*  red  = (float*)(smem + 131072);        // [4][8][32]
    __half* ring = (__half*)(smem + 135168);       // [2][256]

    const int tid  = threadIdx.x;
    const int lane = tid & 63;
    const int wv   = tid >> 6;
    const int g    = blockIdx.x >> 5;
    const int w    = blockIdx.x & 31;

    { // load W_hh fp16 hi/lo slice into LDS, swizzled: byte ^= (row&7)<<4
        const int r  = tid >> 3;
        const int c0 = (tid & 7) * 128;
        const unsigned short* ghi = whh_hi + (size_t)(w * 32 + r) * HID + c0;
        const unsigned short* glo = whh_lo + (size_t)(w * 32 + r) * HID + c0;
        #pragma unroll
        for (int j = 0; j < 16; j++) {
            uint4 vhi = ((const uint4*)ghi)[j];
            uint4 vlo = ((const uint4*)glo)[j];
            int byte = r * 2048 + c0 * 2 + j * 16;
            byte ^= (r & 7) << 4;
            *(uint4*)(smem + byte)         = vhi;
            *(uint4*)(smem + 65536 + byte) = vlo;
        }
    }
    // xp prologue: ring slot 0 = xp[t=0]; issue prefetch of xp[t=1]
    uint4 xn_next;
    if (wv == 0 && tid < 32) {
        const size_t b0 = ((size_t)g * 32 + w) * 256;
        uint4 v0 = ((const uint4*)(xp + b0))[tid];
        *(uint4*)&ring[tid * 8] = v0;
        xn_next = ((const uint4*)(xp + ((size_t)(8 + g) * 32 + (size_t)w) * 256))[tid];
    }
    __syncthreads();

    const bool act = (lane & 15) < 8;
    const int  ar  = lane & 15;
    const int  ak  = (lane >> 4) * 8;
    const float bhh = b_hh[w * 32 + (tid & 31)];
    int* const myflag = flags + g * 32 + w;

    for (int t = 0; t < S_LEN; t++) {
        // 1) poll group flags (lanes<32), first sample issued EARLY; the
        //    ring LDS write executes in its shadow. Spin loop unchanged.
        //    Bound 4096 (~1ms): fast wrong answer on sync failure, no hang.
        if (lane < 32) {
            const int* fp = flags + g * 32 + lane;
            int fv;
            asm volatile("global_load_dword %0, %1, off sc0 sc1"
                         : "=v"(fv) : "v"(fp) : "memory");
            // 2) ring write for t+1 (LDS-only; wv0 subset of polling lanes)
            if (wv == 0 && tid < 32 && t + 1 < S_LEN)
                *(uint4*)&ring[((t + 1) & 1) * 256 + tid * 8] = xn_next;
            asm volatile("s_waitcnt vmcnt(0)" ::: "memory");
            __builtin_amdgcn_sched_barrier(0);     // rule #18
            int spin = 0;
            while (fv < t && ++spin < 4096) {
                asm volatile("global_load_dword %0, %1, off sc0 sc1\n\t"
                             "s_waitcnt vmcnt(0)"
                             : "=v"(fv) : "v"(fp) : "memory");
            }
        }

        // 3) load h_t fragments: single fp16 stream from IC (sc0 sc1), zero
        //    pad for inactive rows. 8x dwordx4 batched, one vmcnt(0).
        const size_t hoff = (size_t)(t & 3) * (BATCH * HID)
                          + (size_t)(g * 8 + (act ? ar : 0)) * HID + wv * 256 + ak;
        const unsigned short* ph = act ? (hbuf + hoff) : (const unsigned short*)zbuf;
        uint4 c[8];
        asm volatile(
            "global_load_dwordx4 %0, %8, off sc0 sc1\n\t"
            "global_load_dwordx4 %1, %8, off offset:64 sc0 sc1\n\t"
            "global_load_dwordx4 %2, %8, off offset:128 sc0 sc1\n\t"
            "global_load_dwordx4 %3, %8, off offset:192 sc0 sc1\n\t"
            "global_load_dwordx4 %4, %8, off offset:256 sc0 sc1\n\t"
            "global_load_dwordx4 %5, %8, off offset:320 sc0 sc1\n\t"
            "global_load_dwordx4 %6, %8, off offset:384 sc0 sc1\n\t"
            "global_load_dwordx4 %7, %8, off offset:448 sc0 sc1\n\t"
            "s_waitcnt vmcnt(0)"
            : "=&v"(c[0]), "=&v"(c[1]), "=&v"(c[2]), "=&v"(c[3]),
              "=&v"(c[4]), "=&v"(c[5]), "=&v"(c[6]), "=&v"(c[7])
            : "v"(ph)
            : "memory");

        // 4) issue xp prefetch for t+2 (plain cached load; a full step of
        //    latency slack before use)
        if (wv == 0 && tid < 32 && t + 2 < S_LEN)
            xn_next = ((const uint4*)(xp
                + ((size_t)((t + 2) * 8 + g) * 32 + (size_t)w) * 256))[tid];

        // 5) fp16 MFMA: h * (W_hi + W_lo), 2 MFMAs per (kk,j)
        f32x4 acc_h[2], acc_l[2];
        #pragma unroll
        for (int j = 0; j < 2; j++) {
            acc_h[j] = (f32x4)0.0f; acc_l[j] = (f32x4)0.0f;
        }
        const int kbyte0 = (wv * 256 + ak) * 2;
        #pragma unroll
        for (int kk = 0; kk < 8; kk++) {
            PunH pa; pa.u = c[kk];
            const half8 af = pa.h;
            #pragma unroll
            for (int j = 0; j < 2; j++) {
                const int rloc = j * 16 + (lane & 15);
                int bb = rloc * 2048 + kbyte0 + kk * 64;
                bb ^= (rloc & 7) << 4;
                PunH pbh; pbh.u = *(const uint4*)(smem + bb);
                PunH pbl; pbl.u = *(const uint4*)(smem + 65536 + bb);
                acc_h[j] = __builtin_amdgcn_mfma_f32_16x16x32_f16(af, pbh.h, acc_h[j], 0, 0, 0);
                acc_l[j] = __builtin_amdgcn_mfma_f32_16x16x32_f16(af, pbl.h, acc_l[j], 0, 0, 0);
            }
        }

        // 6) cross-wave K reduction into LDS
        if (lane < 32) {
            #pragma unroll
            for (int j = 0; j < 2; j++) {
                const f32x4 d = acc_h[j] + acc_l[j];
                const int col = j * 16 + (lane & 15);
                #pragma unroll
                for (int i = 0; i < 4; i++) {
                    const int r = (lane >> 4) * 4 + i;
                    red[(wv * 8 + r) * 32 + col] = d[i];
                }
            }
        }
        __syncthreads();   // barrier A

        // 7) finish: z -> tanh -> fp16 publish + in-asm drain (the drain
        //    must live in the asm: compiler's barrier pass can't see
        //    inline-asm stores).
        {
            const int r = tid >> 5, n = tid & 31;
            float z = red[r * 32 + n] + red[(8 + r) * 32 + n]
                    + red[(16 + r) * 32 + n] + red[(24 + r) * 32 + n];
            z += __half2float(ring[(t & 1) * 256 + tid]) + bhh;
            const float h = tanhf(z);
            const unsigned int hv = __half_as_ushort(__float2half(h));
            const size_t off = (size_t)((t + 1) & 3) * (BATCH * HID)
                             + (size_t)(g * 8 + r) * HID + w * 32 + n;
            asm volatile("global_store_short %0, %1, off sc0 sc1\n\t"
                         "s_waitcnt vmcnt(0)"
                         :: "v"(hbuf + off), "v"(hv) : "memory");
        }
        __syncthreads();   // barrier B: all waves' h stores acknowledged
        if (tid == 0) {
            const int fv2 = t + 1;
            asm volatile("global_store_dword %0, %1, off sc0 sc1"
                         :: "v"(myflag), "v"(fv2) : "memory");
        }
    }
}

// ---------------------------------------------------------------------------
// classifier on h_final (slot (2048&3)=0), fp16 h
// ---------------------------------------------------------------------------
__global__ void cls_kernel(const unsigned short* __restrict__ hbuf,
                           const float* __restrict__ wfc,
                           const float* __restrict__ bfc,
                           float* __restrict__ out)
{
    const int b = blockIdx.x, lane = threadIdx.x;
    const unsigned short* hp = hbuf + (size_t)b * HID;  // slot 0
    float p0 = 0.f, p1 = 0.f;
    for (int k = lane; k < HID; k += 64) {
        const float h = __half2float(__ushort_as_half(hp[k]));
        p0 += h * wfc[k];
        p1 += h * wfc[HID + k];
    }
    #pragma unroll
    for (int s = 32; s; s >>= 1) {
        p0 += __shfl_down(p0, s);
        p1 += __shfl_down(p1, s);
    }
    if (lane == 0) {
        out[b * 2 + 0] = p0 + bfc[0];
        out[b * 2 + 1] = p1 + bfc[1];
    }
}

// ---------------------------------------------------------------------------
extern "C" void kernel_launch(void* const* d_in, const int* in_sizes, int n_in,
                              void* d_out, int out_size, void* d_ws, size_t ws_size,
                              hipStream_t stream)
{
    const int*   tok = (const int*)d_in[0];
    const float* emb = (const float*)d_in[1];
    const float* wih = (const float*)d_in[2];
    const float* whh = (const float*)d_in[3];
    const float* bih = (const float*)d_in[4];
    const float* bhh = (const float*)d_in[5];
    const float* wfc = (const float*)d_in[6];
    const float* bfc = (const float*)d_in[7];
    float* out = (float*)d_out;

    char* ws = (char*)d_ws;
    size_t off = 0;
    auto alloc = [&](size_t bytes) {
        char* p = ws + off;
        off += (bytes + 255) & ~(size_t)255;
        return p;
    };
    __half*         xp      = (__half*)alloc((size_t)S_LEN * BATCH * HID * 2);
    __half*         embh    = (__half*)alloc((size_t)VOC * HID * 2);
    __half*         wihh    = (__half*)alloc((size_t)HID * HID * 2);
    unsigned short* whh_hi  = (unsigned short*)alloc((size_t)HID * HID * 2);
    unsigned short* whh_lo  = (unsigned short*)alloc((size_t)HID * HID * 2);
    unsigned short* hbuf    = (unsigned short*)alloc((size_t)4 * BATCH * HID * 2);
    unsigned int*   zbuf    = (unsigned int*)alloc(1024);
    int*            flags   = (int*)alloc(2048);

    if (off > ws_size) {
        hipMemsetAsync(d_out, 0, (size_t)out_size * sizeof(float), stream);
        return;
    }

    prep_kernel<<<dim3((VOC * HID) / 256), 256, 0, stream>>>(
        emb, wih, whh, embh, wihh, whh_hi, whh_lo, hbuf, zbuf, flags);

    xp_gemm<<<dim3(8, 1024), 256, 0, stream>>>(tok, embh, wihh, bih, xp);

    const unsigned int shmem = 136192;
    hipFuncSetAttribute(reinterpret_cast<const void*>(recur_kernel),
                        hipFuncAttributeMaxDynamicSharedMemorySize, (int)shmem);
    void* args[] = { (void*)&xp, (void*)&whh_hi, (void*)&whh_lo, (void*)&bhh,
                     (void*)&hbuf, (void*)&zbuf, (void*)&flags };
    hipLaunchCooperativeKernel(reinterpret_cast<const void*>(recur_kernel),
                               dim3(256), dim3(256), args, shmem, stream);

    cls_kernel<<<dim3(64), 64, 0, stream>>>(hbuf, wfc, bfc, out);
}